// Round 1
// baseline (131.689 us; speedup 1.0000x reference)
//
#include <hip/hip_runtime.h>

typedef unsigned short u16;
typedef __bf16 bf16x8 __attribute__((ext_vector_type(8)));
typedef float f32x4 __attribute__((ext_vector_type(4)));

union B8 {
    bf16x8 v;
    u16 s[8];
    uint4 u4;
};

__device__ __forceinline__ u16 f2bf(float f) {
    unsigned u = __float_as_uint(f);
    return (u16)((u + 0x7fffu + ((u >> 16) & 1u)) >> 16);
}
__device__ __forceinline__ unsigned pack2(float a, float b) {
    return (unsigned)f2bf(a) | ((unsigned)f2bf(b) << 16);
}
__device__ __forceinline__ B8 load_w8(const float* __restrict__ p) {
    float4 lo = ((const float4*)p)[0];
    float4 hi = ((const float4*)p)[1];
    B8 r;
    r.s[0] = f2bf(lo.x); r.s[1] = f2bf(lo.y); r.s[2] = f2bf(lo.z); r.s[3] = f2bf(lo.w);
    r.s[4] = f2bf(hi.x); r.s[5] = f2bf(hi.y); r.s[6] = f2bf(hi.z); r.s[7] = f2bf(hi.w);
    return r;
}
__device__ __forceinline__ f32x4 mfma16(const B8 a, const B8 b, f32x4 c) {
    return __builtin_amdgcn_mfma_f32_16x16x32_bf16(a.v, b.v, c, 0, 0, 0);
}

// LDS map (ushort indices).  Total 140,288 bytes.
//   K   [512 tok][32 ck]          @ 0      (32768 B)
//   V   [64 cv][520 tok(+pad)]    @ 16384  (66560 B)
//   P   8 waves x [64 q][40 m]    @ 49664  (40960 B)   (X-chunk [128][72] overlays this in proj phase)
//   slots: 8 waves x 16384 B @ byte 0 (ctx bf16 [64 q][72 cv], then out f32 [64 co][64 q]) - after attention
#define KOFF 0
#define VOFF 16384
#define POFF 49664
#define NSM  70144

__global__ __launch_bounds__(512, 1)
void psab_fused(const float* __restrict__ x,
                const float* __restrict__ wk, const float* __restrict__ bk,
                const float* __restrict__ wv, const float* __restrict__ bv,
                const float* __restrict__ wo, const float* __restrict__ bo,
                float* __restrict__ out)
{
    __shared__ __align__(16) u16 smem[NSM];
    const int t    = threadIdx.x;
    const int lane = t & 63;
    const int wid  = t >> 6;       // 8 waves; wave = hb (h-within-window)
    const int lr   = lane & 15;
    const int lq   = lane >> 4;

    // XCD-bijective swizzle: consecutive windows (adjacent sd -> shared L2 lines) per XCD
    const int bid = blockIdx.x;
    const int n   = (bid & 7) * 64 + (bid >> 3);
    const int sh = n >> 6, sw = (n >> 3) & 7, sd = n & 7;
    const size_t base_vox = (size_t)(sh * 8) * 4096 + (size_t)(sw * 8) * 64 + (size_t)(sd * 8);

    // ---- weight B-fragments for K/V proj: B[k=c][n=ck] = w[ck*64+c] ----
    B8 wkB[2][2], wvB[2][4];
#pragma unroll
    for (int kt = 0; kt < 2; ++kt)
#pragma unroll
        for (int nt = 0; nt < 2; ++nt)
            wkB[kt][nt] = load_w8(wk + (nt * 16 + lr) * 64 + kt * 32 + lq * 8);
#pragma unroll
    for (int kt = 0; kt < 2; ++kt)
#pragma unroll
        for (int nt = 0; nt < 4; ++nt)
            wvB[kt][nt] = load_w8(wv + (nt * 16 + lr) * 64 + kt * 32 + lq * 8);
    float kbias[2], vbias[4];
#pragma unroll
    for (int nt = 0; nt < 2; ++nt) kbias[nt] = bk[nt * 16 + lr];
#pragma unroll
    for (int nt = 0; nt < 4; ++nt) vbias[nt] = bv[nt * 16 + lr];

    // ---- projection phase: 4 chunks of 128 tokens ----
    const int cS = t & 63;     // staging channel
    const int r2 = t >> 6;     // staging row group
    for (int cc = 0; cc < 4; ++cc) {
        __syncthreads();   // previous chunk's X readers done
#pragma unroll
        for (int half = 0; half < 2; ++half) {
            const int rr = r2 + half * 8;              // 0..15 (hb_local, wb)
            const int hb = cc * 2 + (rr >> 3);
            const int wb = rr & 7;
            const float* gp = x + (size_t)cS * 262144 + base_vox + hb * 4096 + wb * 64;
            float4 lo = ((const float4*)gp)[0];
            float4 hi = ((const float4*)gp)[1];
            u16* xp = &smem[POFF + (rr * 8) * 72 + cS];   // X[tok][c], stride 72
            xp[0 * 72] = f2bf(lo.x); xp[1 * 72] = f2bf(lo.y);
            xp[2 * 72] = f2bf(lo.z); xp[3 * 72] = f2bf(lo.w);
            xp[4 * 72] = f2bf(hi.x); xp[5 * 72] = f2bf(hi.y);
            xp[6 * 72] = f2bf(hi.z); xp[7 * 72] = f2bf(hi.w);
        }
        __syncthreads();   // X chunk visible
        B8 xa[2];
        const int tokA = wid * 16 + lr;
        xa[0].u4 = *(const uint4*)&smem[POFF + tokA * 72 + 0 * 32 + lq * 8];
        xa[1].u4 = *(const uint4*)&smem[POFF + tokA * 72 + 1 * 32 + lq * 8];
        const int tg = cc * 128 + wid * 16 + lq * 4;   // D rows: 4 consecutive tokens
        const f32x4 z = {0.f, 0.f, 0.f, 0.f};
#pragma unroll
        for (int nt = 0; nt < 2; ++nt) {               // K proj -> K[tok][ck]
            f32x4 kd = z;
            kd = mfma16(xa[0], wkB[0][nt], kd);
            kd = mfma16(xa[1], wkB[1][nt], kd);
            const int ck = nt * 16 + lr;
            smem[KOFF + (tg + 0) * 32 + ck] = f2bf(kd[0] + kbias[nt]);
            smem[KOFF + (tg + 1) * 32 + ck] = f2bf(kd[1] + kbias[nt]);
            smem[KOFF + (tg + 2) * 32 + ck] = f2bf(kd[2] + kbias[nt]);
            smem[KOFF + (tg + 3) * 32 + ck] = f2bf(kd[3] + kbias[nt]);
        }
#pragma unroll
        for (int nt = 0; nt < 4; ++nt) {               // V proj -> V[cv][tok]
            f32x4 vd = z;
            vd = mfma16(xa[0], wvB[0][nt], vd);
            vd = mfma16(xa[1], wvB[1][nt], vd);
            const int cv = nt * 16 + lr;
            uint2 pk;
            pk.x = pack2(vd[0] + vbias[nt], vd[1] + vbias[nt]);
            pk.y = pack2(vd[2] + vbias[nt], vd[3] + vbias[nt]);
            *(uint2*)&smem[VOFF + cv * 520 + tg] = pk;
        }
    }
    __syncthreads();   // K/V complete

    // ---- attention: wave owns 64 q (q = wid*64 + nt*16 + lr); chunks of 32 m ----
    B8 qb[4];
#pragma unroll
    for (int nt = 0; nt < 4; ++nt)
        qb[nt].u4 = *(const uint4*)&smem[KOFF + (wid * 64 + nt * 16 + lr) * 32 + lq * 8];

    const f32x4 z = {0.f, 0.f, 0.f, 0.f};
    f32x4 ctx[4][4];
#pragma unroll
    for (int ct = 0; ct < 4; ++ct)
#pragma unroll
        for (int nt = 0; nt < 4; ++nt) ctx[ct][nt] = z;
    float mrun[4] = {-1e30f, -1e30f, -1e30f, -1e30f};
    float lrun[4] = {0.f, 0.f, 0.f, 0.f};
    const float Cs = 0.25508894f;   // log2(e)/sqrt(32)
    const int prow = POFF + wid * 2560;

    for (int ci = 0; ci < 16; ++ci) {
        const int m0 = ci * 32;
        B8 ka0, ka1;
        ka0.u4 = *(const uint4*)&smem[KOFF + (m0 + lr) * 32 + lq * 8];
        ka1.u4 = *(const uint4*)&smem[KOFF + (m0 + 16 + lr) * 32 + lq * 8];
#pragma unroll
        for (int nt = 0; nt < 4; ++nt) {
            // S^T[m][q]: rows = m (in-lane), cols = q
            f32x4 s0 = mfma16(ka0, qb[nt], z);
            f32x4 s1 = mfma16(ka1, qb[nt], z);
            float cmax = fmaxf(fmaxf(fmaxf(s0[0], s0[1]), fmaxf(s0[2], s0[3])),
                               fmaxf(fmaxf(s1[0], s1[1]), fmaxf(s1[2], s1[3])));
            cmax = fmaxf(cmax, __shfl_xor(cmax, 16));
            cmax = fmaxf(cmax, __shfl_xor(cmax, 32));
            const float mnew = fmaxf(mrun[nt], cmax);
            const float sc = exp2f((mrun[nt] - mnew) * Cs);
            const float mc = mnew * Cs;
            float p0 = exp2f(fmaf(s0[0], Cs, -mc));
            float p1 = exp2f(fmaf(s0[1], Cs, -mc));
            float p2 = exp2f(fmaf(s0[2], Cs, -mc));
            float p3 = exp2f(fmaf(s0[3], Cs, -mc));
            float p4 = exp2f(fmaf(s1[0], Cs, -mc));
            float p5 = exp2f(fmaf(s1[1], Cs, -mc));
            float p6 = exp2f(fmaf(s1[2], Cs, -mc));
            float p7 = exp2f(fmaf(s1[3], Cs, -mc));
            float ps = ((p0 + p1) + (p2 + p3)) + ((p4 + p5) + (p6 + p7));
            ps += __shfl_xor(ps, 16);
            ps += __shfl_xor(ps, 32);
            lrun[nt] = lrun[nt] * sc + ps;
            mrun[nt] = mnew;
#pragma unroll
            for (int ct = 0; ct < 4; ++ct) ctx[ct][nt] *= sc;
            u16* pr = &smem[prow + (nt * 16 + lr) * 40];
            uint2 pkA, pkB;
            pkA.x = pack2(p0, p1); pkA.y = pack2(p2, p3);
            pkB.x = pack2(p4, p5); pkB.y = pack2(p6, p7);
            *(uint2*)&pr[0 * 16 + lq * 4] = pkA;
            *(uint2*)&pr[1 * 16 + lq * 4] = pkB;
        }
        // PV: ctx^T[cv][q] += V^T[cv][m-chunk] * P^T[m-chunk][q]
        B8 va[4], pb[4];
#pragma unroll
        for (int ct = 0; ct < 4; ++ct)
            va[ct].u4 = *(const uint4*)&smem[VOFF + (ct * 16 + lr) * 520 + m0 + lq * 8];
#pragma unroll
        for (int nt = 0; nt < 4; ++nt)
            pb[nt].u4 = *(const uint4*)&smem[prow + (nt * 16 + lr) * 40 + lq * 8];
#pragma unroll
        for (int ct = 0; ct < 4; ++ct)
#pragma unroll
            for (int nt = 0; nt < 4; ++nt)
                ctx[ct][nt] = mfma16(va[ct], pb[nt], ctx[ct][nt]);
    }

    __syncthreads();   // everyone done reading K/V/P; slots become free

    // ---- epilogue: ctx -> slot (bf16 [q][72]), out-proj MFMA, out f32 [co][64], coalesced store ----
    const int SLOT = wid * 8192;   // ushort index; 16 KB per wave
#pragma unroll
    for (int nt = 0; nt < 4; ++nt) {
        const float inv = 1.0f / lrun[nt];
        u16* cr = &smem[SLOT + (nt * 16 + lr) * 72];
#pragma unroll
        for (int ct = 0; ct < 4; ++ct) {
            f32x4 c4 = ctx[ct][nt];
            uint2 pk;
            pk.x = pack2(c4[0] * inv, c4[1] * inv);
            pk.y = pack2(c4[2] * inv, c4[3] * inv);
            *(uint2*)&cr[ct * 16 + lq * 4] = pk;
        }
    }
    B8 woA[4][2], cbf[2][4];
#pragma unroll
    for (int mt = 0; mt < 4; ++mt)
#pragma unroll
        for (int kt = 0; kt < 2; ++kt)
            woA[mt][kt] = load_w8(wo + (mt * 16 + lr) * 64 + kt * 32 + lq * 8);
#pragma unroll
    for (int kt = 0; kt < 2; ++kt)
#pragma unroll
        for (int nt = 0; nt < 4; ++nt)
            cbf[kt][nt].u4 = *(const uint4*)&smem[SLOT + (nt * 16 + lr) * 72 + kt * 32 + lq * 8];

    float* fout = (float*)&smem[SLOT];   // [64 co][64 q] f32, overwrites ctx (in-wave ordered)
#pragma unroll
    for (int mt = 0; mt < 4; ++mt) {
        const float4 b4 = *(const float4*)(bo + mt * 16 + lq * 4);
#pragma unroll
        for (int nt = 0; nt < 4; ++nt) {
            f32x4 od = z;
            od = mfma16(woA[mt][0], cbf[0][nt], od);
            od = mfma16(woA[mt][1], cbf[1][nt], od);
            const int col = nt * 16 + lr;
            fout[(mt * 16 + lq * 4 + 0) * 64 + col] = od[0] + b4.x;
            fout[(mt * 16 + lq * 4 + 1) * 64 + col] = od[1] + b4.y;
            fout[(mt * 16 + lq * 4 + 2) * 64 + col] = od[2] + b4.z;
            fout[(mt * 16 + lq * 4 + 3) * 64 + col] = od[3] + b4.w;
        }
    }
    // global store: wave wid = hb row; q = wb*8+db, float4 along d
    float* outw = out + base_vox + (size_t)wid * 4096;
#pragma unroll
    for (int it = 0; it < 16; ++it) {
        const int co = it * 4 + lq;
        const float4 v4 = *(const float4*)&fout[co * 64 + lr * 4];
        const int wb = lr >> 1, db0 = (lr & 1) * 4;
        *(float4*)&outw[(size_t)co * 262144 + wb * 64 + db0] = v4;
    }
}

extern "C" void kernel_launch(void* const* d_in, const int* in_sizes, int n_in,
                              void* d_out, int out_size, void* d_ws, size_t ws_size,
                              hipStream_t stream) {
    const float* x  = (const float*)d_in[0];
    const float* wk = (const float*)d_in[1];
    const float* bk = (const float*)d_in[2];
    const float* wv = (const float*)d_in[3];
    const float* bv = (const float*)d_in[4];
    const float* wo = (const float*)d_in[5];
    const float* bo = (const float*)d_in[6];
    float* o = (float*)d_out;
    psab_fused<<<dim3(512), dim3(512), 0, stream>>>(x, wk, bk, wv, bv, wo, bo, o);
}

// Round 2
// 76.983 us; speedup vs baseline: 1.7106x; 1.7106x over previous
//
#include <hip/hip_runtime.h>

typedef unsigned short u16;
typedef __bf16 bf16x8 __attribute__((ext_vector_type(8)));
typedef float f32x4 __attribute__((ext_vector_type(4)));

union B8 {
    bf16x8 v;
    u16 s[8];
    unsigned u[4];
    uint4 u4;
};

__device__ __forceinline__ unsigned cvtpk(float a, float b) {
    unsigned r;
    asm("v_cvt_pk_bf16_f32 %0, %1, %2" : "=v"(r) : "v"(a), "v"(b));
    return r;   // lo16 = bf16(a), hi16 = bf16(b)
}
__device__ __forceinline__ float ex2(float x) {
    return __builtin_amdgcn_exp2f(x);
}
__device__ __forceinline__ B8 load_w8(const float* __restrict__ p, float s) {
    float4 lo = ((const float4*)p)[0];
    float4 hi = ((const float4*)p)[1];
    B8 r;
    r.u[0] = cvtpk(lo.x * s, lo.y * s);
    r.u[1] = cvtpk(lo.z * s, lo.w * s);
    r.u[2] = cvtpk(hi.x * s, hi.y * s);
    r.u[3] = cvtpk(hi.z * s, hi.w * s);
    return r;
}
__device__ __forceinline__ f32x4 mfma16(const B8 a, const B8 b, f32x4 c) {
    return __builtin_amdgcn_mfma_f32_16x16x32_bf16(a.v, b.v, c, 0, 0, 0);
}
// K LDS layout: row tok = 64B (32 ck u16), 16B slots XOR-swizzled by (tok>>1)&3.
__device__ __forceinline__ int kidx(int tok, int slot) {   // u16 index, slot = logical ck>>3
    return tok * 32 + ((slot ^ ((tok >> 1) & 3)) << 3);
}

// LDS map (ushort indices). Total 140,288 bytes.
//   K   [512 tok][32 ck] swizzled  @ 0      (32768 B)
//   V   [64 cv][520 tok(+pad)]     @ 16384  (66560 B)
//   P   8 waves x [64 q][40 m]     @ 49664  (40960 B)  (X-chunk [128][72] overlays in proj phase)
//   slots: 8 waves x 16384 B @ 0 (ctx bf16 [64 q][72 cv] then out f32 [64 co][64 q]) after attention
#define KOFF 0
#define VOFF 16384
#define POFF 49664
#define NSM  70144

__global__ __launch_bounds__(512, 1)
void psab_fused(const float* __restrict__ x,
                const float* __restrict__ wk, const float* __restrict__ bk,
                const float* __restrict__ wv, const float* __restrict__ bv,
                const float* __restrict__ wo, const float* __restrict__ bo,
                float* __restrict__ out)
{
    __shared__ __align__(16) u16 smem[NSM];
    const int t    = threadIdx.x;
    const int lane = t & 63;
    const int wid  = t >> 6;       // 8 waves; wave = hb (h-within-window)
    const int lr   = lane & 15;
    const int lq   = lane >> 4;

    // XCD-bijective swizzle: consecutive windows (adjacent sd -> shared L2 lines) per XCD
    const int bid = blockIdx.x;
    const int n   = (bid & 7) * 64 + (bid >> 3);
    const int sh = n >> 6, sw = (n >> 3) & 7, sd = n & 7;
    const size_t base_vox = (size_t)(sh * 8) * 4096 + (size_t)(sw * 8) * 64 + (size_t)(sd * 8);

    // sqrt(log2(e)/sqrt(32)) folded into K-proj weights: MFMA scores come out log2-domain.
    const float WSC = 0.50506330f;

    B8 wkB[2][2], wvB[2][4];
#pragma unroll
    for (int kt = 0; kt < 2; ++kt)
#pragma unroll
        for (int nt = 0; nt < 2; ++nt)
            wkB[kt][nt] = load_w8(wk + (nt * 16 + lr) * 64 + kt * 32 + lq * 8, WSC);
#pragma unroll
    for (int kt = 0; kt < 2; ++kt)
#pragma unroll
        for (int nt = 0; nt < 4; ++nt)
            wvB[kt][nt] = load_w8(wv + (nt * 16 + lr) * 64 + kt * 32 + lq * 8, 1.0f);
    float kbias[2], vbias[4];
#pragma unroll
    for (int nt = 0; nt < 2; ++nt) kbias[nt] = bk[nt * 16 + lr] * WSC;
#pragma unroll
    for (int nt = 0; nt < 4; ++nt) vbias[nt] = bv[nt * 16 + lr];

    const f32x4 z = {0.f, 0.f, 0.f, 0.f};

    // ---- projection phase: 4 chunks of 128 tokens, X loads pipelined ----
    const int cS = t & 63;     // staging channel
    const int r2 = t >> 6;     // staging row group
    float4 Lo[2], Hi[2];
#define LDX(cc)                                                                   \
    _Pragma("unroll")                                                             \
    for (int half = 0; half < 2; ++half) {                                        \
        const int rr = r2 + half * 8;                                             \
        const int hb = (cc) * 2 + (rr >> 3);                                      \
        const int wb = rr & 7;                                                    \
        const float* gp = x + (size_t)cS * 262144 + base_vox + hb * 4096 + wb * 64; \
        Lo[half] = ((const float4*)gp)[0];                                        \
        Hi[half] = ((const float4*)gp)[1];                                        \
    }

    LDX(0)
    for (int cc = 0; cc < 4; ++cc) {
        __syncthreads();   // previous chunk's X readers done
#pragma unroll
        for (int half = 0; half < 2; ++half) {
            const int rr = r2 + half * 8;
            unsigned a0 = cvtpk(Lo[half].x, Lo[half].y);
            unsigned a1 = cvtpk(Lo[half].z, Lo[half].w);
            unsigned a2 = cvtpk(Hi[half].x, Hi[half].y);
            unsigned a3 = cvtpk(Hi[half].z, Hi[half].w);
            u16* xp = &smem[POFF + (rr * 8) * 72 + cS];   // X[tok][c], stride 72
            xp[0 * 72] = (u16)a0; xp[1 * 72] = (u16)(a0 >> 16);
            xp[2 * 72] = (u16)a1; xp[3 * 72] = (u16)(a1 >> 16);
            xp[4 * 72] = (u16)a2; xp[5 * 72] = (u16)(a2 >> 16);
            xp[6 * 72] = (u16)a3; xp[7 * 72] = (u16)(a3 >> 16);
        }
        __syncthreads();   // X chunk visible
        if (cc < 3) { LDX(cc + 1) }   // issue next chunk's loads; overlap with MFMAs below
        B8 xa[2];
        const int tokA = wid * 16 + lr;
        xa[0].u4 = *(const uint4*)&smem[POFF + tokA * 72 + 0 * 32 + lq * 8];
        xa[1].u4 = *(const uint4*)&smem[POFF + tokA * 72 + 1 * 32 + lq * 8];
        const int tg = cc * 128 + wid * 16 + lq * 4;   // D rows: 4 consecutive tokens
#pragma unroll
        for (int nt = 0; nt < 2; ++nt) {               // K proj -> K[tok][ck] (swizzled)
            f32x4 kd = z;
            kd = mfma16(xa[0], wkB[0][nt], kd);
            kd = mfma16(xa[1], wkB[1][nt], kd);
            const int slot = nt * 2 + (lr >> 3);
            const int cko  = lr & 7;
            unsigned p01 = cvtpk(kd[0] + kbias[nt], kd[1] + kbias[nt]);
            unsigned p23 = cvtpk(kd[2] + kbias[nt], kd[3] + kbias[nt]);
            smem[KOFF + kidx(tg + 0, slot) + cko] = (u16)p01;
            smem[KOFF + kidx(tg + 1, slot) + cko] = (u16)(p01 >> 16);
            smem[KOFF + kidx(tg + 2, slot) + cko] = (u16)p23;
            smem[KOFF + kidx(tg + 3, slot) + cko] = (u16)(p23 >> 16);
        }
#pragma unroll
        for (int nt = 0; nt < 4; ++nt) {               // V proj -> V[cv][tok]
            f32x4 vd = z;
            vd = mfma16(xa[0], wvB[0][nt], vd);
            vd = mfma16(xa[1], wvB[1][nt], vd);
            const int cv = nt * 16 + lr;
            uint2 pk;
            pk.x = cvtpk(vd[0] + vbias[nt], vd[1] + vbias[nt]);
            pk.y = cvtpk(vd[2] + vbias[nt], vd[3] + vbias[nt]);
            *(uint2*)&smem[VOFF + cv * 520 + tg] = pk;
        }
    }
    __syncthreads();   // K/V complete

    // ---- attention: wave owns 64 q; no running max (scores bounded); l via ones-MFMA ----
    B8 qb[4];
#pragma unroll
    for (int nt = 0; nt < 4; ++nt)
        qb[nt].u4 = *(const uint4*)&smem[KOFF + kidx(wid * 64 + nt * 16 + lr, lq)];

    B8 ones;
    ones.u[0] = 0x3f803f80u; ones.u[1] = 0x3f803f80u;
    ones.u[2] = 0x3f803f80u; ones.u[3] = 0x3f803f80u;

    f32x4 ctx[4][4], lacc[4];
#pragma unroll
    for (int nt = 0; nt < 4; ++nt) {
        lacc[nt] = z;
#pragma unroll
        for (int ct = 0; ct < 4; ++ct) ctx[ct][nt] = z;
    }
    const int prow = POFF + wid * 2560;

#pragma unroll 2
    for (int ci = 0; ci < 16; ++ci) {
        const int m0 = ci * 32;
        B8 ka0, ka1;
        ka0.u4 = *(const uint4*)&smem[KOFF + kidx(m0 + lr, lq)];
        ka1.u4 = *(const uint4*)&smem[KOFF + kidx(m0 + 16 + lr, lq)];
#pragma unroll
        for (int nt = 0; nt < 4; ++nt) {
            // S^T[m][q] in log2 domain (scale folded into wk)
            f32x4 s0 = mfma16(ka0, qb[nt], z);
            f32x4 s1 = mfma16(ka1, qb[nt], z);
            uint2 pkA, pkB;
            pkA.x = cvtpk(ex2(s0[0]), ex2(s0[1]));
            pkA.y = cvtpk(ex2(s0[2]), ex2(s0[3]));
            pkB.x = cvtpk(ex2(s1[0]), ex2(s1[1]));
            pkB.y = cvtpk(ex2(s1[2]), ex2(s1[3]));
            u16* pr = &smem[prow + (nt * 16 + lr) * 40];
            *(uint2*)&pr[0 * 16 + lq * 4] = pkA;
            *(uint2*)&pr[1 * 16 + lq * 4] = pkB;
        }
        // PV: ctx^T[cv][q] += V^T[cv][m] * P^T[m][q];  l[q] += 1·P
        B8 va[4], pb[4];
#pragma unroll
        for (int ct = 0; ct < 4; ++ct)
            va[ct].u4 = *(const uint4*)&smem[VOFF + (ct * 16 + lr) * 520 + m0 + lq * 8];
#pragma unroll
        for (int nt = 0; nt < 4; ++nt)
            pb[nt].u4 = *(const uint4*)&smem[prow + (nt * 16 + lr) * 40 + lq * 8];
#pragma unroll
        for (int nt = 0; nt < 4; ++nt)
            lacc[nt] = mfma16(ones, pb[nt], lacc[nt]);
#pragma unroll
        for (int ct = 0; ct < 4; ++ct)
#pragma unroll
            for (int nt = 0; nt < 4; ++nt)
                ctx[ct][nt] = mfma16(va[ct], pb[nt], ctx[ct][nt]);
    }

    __syncthreads();   // everyone done reading K/V/P; slots become free

    // ---- epilogue: ctx -> slot (bf16 [q][72]), out-proj MFMA, out f32 [co][64], coalesced store ----
    const int SLOT = wid * 8192;   // ushort index; 16 KB per wave
#pragma unroll
    for (int nt = 0; nt < 4; ++nt) {
        const float inv = 1.0f / lacc[nt][0];
        u16* cr = &smem[SLOT + (nt * 16 + lr) * 72];
#pragma unroll
        for (int ct = 0; ct < 4; ++ct) {
            f32x4 c4 = ctx[ct][nt];
            uint2 pk;
            pk.x = cvtpk(c4[0] * inv, c4[1] * inv);
            pk.y = cvtpk(c4[2] * inv, c4[3] * inv);
            *(uint2*)&cr[ct * 16 + lq * 4] = pk;
        }
    }
    B8 woA[4][2], cbf[2][4];
#pragma unroll
    for (int mt = 0; mt < 4; ++mt)
#pragma unroll
        for (int kt = 0; kt < 2; ++kt)
            woA[mt][kt] = load_w8(wo + (mt * 16 + lr) * 64 + kt * 32 + lq * 8, 1.0f);
#pragma unroll
    for (int kt = 0; kt < 2; ++kt)
#pragma unroll
        for (int nt = 0; nt < 4; ++nt)
            cbf[kt][nt].u4 = *(const uint4*)&smem[SLOT + (nt * 16 + lr) * 72 + kt * 32 + lq * 8];

    float* fout = (float*)&smem[SLOT];   // [64 co][64 q] f32, overwrites ctx (in-wave ordered)
#pragma unroll
    for (int mt = 0; mt < 4; ++mt) {
        const float4 b4 = *(const float4*)(bo + mt * 16 + lq * 4);
#pragma unroll
        for (int nt = 0; nt < 4; ++nt) {
            f32x4 od = z;
            od = mfma16(woA[mt][0], cbf[0][nt], od);
            od = mfma16(woA[mt][1], cbf[1][nt], od);
            const int col = nt * 16 + lr;
            fout[(mt * 16 + lq * 4 + 0) * 64 + col] = od[0] + b4.x;
            fout[(mt * 16 + lq * 4 + 1) * 64 + col] = od[1] + b4.y;
            fout[(mt * 16 + lq * 4 + 2) * 64 + col] = od[2] + b4.z;
            fout[(mt * 16 + lq * 4 + 3) * 64 + col] = od[3] + b4.w;
        }
    }
    // global store: wave wid = hb row; q = wb*8+db, float4 along d
    float* outw = out + base_vox + (size_t)wid * 4096;
#pragma unroll
    for (int it = 0; it < 16; ++it) {
        const int co = it * 4 + lq;
        const float4 v4 = *(const float4*)&fout[co * 64 + lr * 4];
        const int wb = lr >> 1, db0 = (lr & 1) * 4;
        *(float4*)&outw[(size_t)co * 262144 + wb * 64 + db0] = v4;
    }
}

extern "C" void kernel_launch(void* const* d_in, const int* in_sizes, int n_in,
                              void* d_out, int out_size, void* d_ws, size_t ws_size,
                              hipStream_t stream) {
    const float* x  = (const float*)d_in[0];
    const float* wk = (const float*)d_in[1];
    const float* bk = (const float*)d_in[2];
    const float* wv = (const float*)d_in[3];
    const float* bv = (const float*)d_in[4];
    const float* wo = (const float*)d_in[5];
    const float* bo = (const float*)d_in[6];
    float* o = (float*)d_out;
    psab_fused<<<dim3(512), dim3(512), 0, stream>>>(x, wk, bk, wv, bv, wo, bo, o);
}

// Round 3
// 72.336 us; speedup vs baseline: 1.8205x; 1.0642x over previous
//
#include <hip/hip_runtime.h>

typedef unsigned short u16;
typedef __bf16 bf16x8 __attribute__((ext_vector_type(8)));
typedef float f32x16 __attribute__((ext_vector_type(16)));

union B8 { bf16x8 v; u16 s[8]; unsigned u[4]; uint4 u4; };

__device__ __forceinline__ unsigned cvtpk(float a, float b) {
    unsigned r;
    asm("v_cvt_pk_bf16_f32 %0, %1, %2" : "=v"(r) : "v"(a), "v"(b));
    return r;   // lo16 = bf16(a), hi16 = bf16(b)
}
__device__ __forceinline__ float ex2(float x) { return __builtin_amdgcn_exp2f(x); }
__device__ __forceinline__ void swap32(unsigned &a, unsigned &b) {
    // exchanges a's hi-32-lane values with b's lo-32-lane values
    asm("v_permlane32_swap_b32 %0, %1" : "+v"(a), "+v"(b));
}
__device__ __forceinline__ B8 load_w8(const float* __restrict__ p, float s) {
    float4 lo = ((const float4*)p)[0];
    float4 hi = ((const float4*)p)[1];
    B8 r;
    r.u[0] = cvtpk(lo.x * s, lo.y * s);
    r.u[1] = cvtpk(lo.z * s, lo.w * s);
    r.u[2] = cvtpk(hi.x * s, hi.y * s);
    r.u[3] = cvtpk(hi.z * s, hi.w * s);
    return r;
}
__device__ __forceinline__ f32x16 mfma32(const B8 a, const B8 b, f32x16 c) {
    return __builtin_amdgcn_mfma_f32_32x32x16_bf16(a.v, b.v, c, 0, 0, 0);
}
// K LDS: [512 tok][32 ck] u16, 4x16B slots per row XOR-swizzled by (tok>>1)&3
__device__ __forceinline__ int kidx(int row, int sl) {
    return row * 32 + (((sl ^ (row >> 1)) & 3) << 3);
}
// D-regs (rows (r&3)+8*(r>>2)+4*h5) -> two B-fragments (k-chunks of 16) via cvtpk+permlane
__device__ __forceinline__ void build_b(const float* p, B8& b0, B8& b1) {
    unsigned c0 = cvtpk(p[0], p[1]),   c1 = cvtpk(p[2], p[3]);
    unsigned c2 = cvtpk(p[4], p[5]),   c3 = cvtpk(p[6], p[7]);
    unsigned c4 = cvtpk(p[8], p[9]),   c5 = cvtpk(p[10], p[11]);
    unsigned c6 = cvtpk(p[12], p[13]), c7 = cvtpk(p[14], p[15]);
    swap32(c0, c2); swap32(c1, c3); swap32(c4, c6); swap32(c5, c7);
    b0.u[0] = c0; b0.u[1] = c1; b0.u[2] = c2; b0.u[3] = c3;
    b1.u[0] = c4; b1.u[1] = c5; b1.u[2] = c6; b1.u[3] = c7;
}

// LDS (u16 idx): K [512][32] @0 (32768B) | V [64][520] @16384 (66560B) | X [256][72] @49664 (36864B)
// epilogue: 8 wave-slots of 16KB f32 fout overlay @byte 0 (after barrier 5)
#define VOFF 16384
#define XOFF 49664
#define NSM  68096

__global__ __launch_bounds__(512, 1)
void psab_fused(const float* __restrict__ x,
                const float* __restrict__ wk, const float* __restrict__ bk,
                const float* __restrict__ wv, const float* __restrict__ bv,
                const float* __restrict__ wo, const float* __restrict__ bo,
                float* __restrict__ out)
{
    __shared__ __align__(16) u16 smem[NSM];
    const int t    = threadIdx.x;
    const int lane = t & 63;
    const int wid  = t >> 6;       // wave = hb row of the window
    const int cl   = lane & 31;
    const int h5   = lane >> 5;

    const int bid = blockIdx.x;
    const int n   = (bid & 7) * 64 + (bid >> 3);   // XCD-bijective swizzle
    const int sh = n >> 6, sw = (n >> 3) & 7, sd = n & 7;
    const size_t base_vox = (size_t)(sh * 8) * 4096 + (size_t)(sw * 8) * 64 + (size_t)(sd * 8);

    const float WSC = 0.50506330f;   // sqrt(log2(e)/sqrt(32)) folded into K weights

    B8 wkB[4], wvB[2][4];
#pragma unroll
    for (int kc = 0; kc < 4; ++kc)
        wkB[kc] = load_w8(wk + cl * 64 + kc * 16 + h5 * 8, WSC);
#pragma unroll
    for (int nb = 0; nb < 2; ++nb)
#pragma unroll
        for (int kc = 0; kc < 4; ++kc)
            wvB[nb][kc] = load_w8(wv + (nb * 32 + cl) * 64 + kc * 16 + h5 * 8, 1.0f);
    const float kbias = bk[cl] * WSC;
    const float vbias[2] = { bv[cl], bv[32 + cl] };

    const f32x16 z16 = {0,0,0,0,0,0,0,0,0,0,0,0,0,0,0,0};

    // ---- X staging: 2 chunks x 256 tok (4 hb x 8 wb x 8 db); thread (cS,r2) ----
    const int cS = t & 63;
    const int r2 = t >> 6;
    float4 L4[4], H4[4];
#define LDX(cc)                                                                              \
    _Pragma("unroll")                                                                        \
    for (int i = 0; i < 4; ++i) {                                                            \
        const float* gp = x + (size_t)cS * 262144 + base_vox + ((cc) * 4 + i) * 4096 + r2 * 64; \
        L4[i] = ((const float4*)gp)[0];                                                      \
        H4[i] = ((const float4*)gp)[1];                                                      \
    }
#define STX()                                                                                \
    _Pragma("unroll")                                                                        \
    for (int i = 0; i < 4; ++i) {                                                            \
        unsigned a0 = cvtpk(L4[i].x, L4[i].y), a1 = cvtpk(L4[i].z, L4[i].w);                 \
        unsigned a2 = cvtpk(H4[i].x, H4[i].y), a3 = cvtpk(H4[i].z, H4[i].w);                 \
        u16* xp = &smem[XOFF + (i * 64 + r2 * 8) * 72 + cS];                                 \
        xp[0 * 72] = (u16)a0; xp[1 * 72] = (u16)(a0 >> 16);                                  \
        xp[2 * 72] = (u16)a1; xp[3 * 72] = (u16)(a1 >> 16);                                  \
        xp[4 * 72] = (u16)a2; xp[5 * 72] = (u16)(a2 >> 16);                                  \
        xp[6 * 72] = (u16)a3; xp[7 * 72] = (u16)(a3 >> 16);                                  \
    }

    LDX(0)
    STX()
    __syncthreads();                          // (1) X0 visible
    LDX(1)                                    // prefetch chunk1 under proj-chunk0 compute

#pragma unroll
    for (int cc = 0; cc < 2; ++cc) {
        const int tokb = cc * 256 + wid * 32;
        B8 ax[4];
#pragma unroll
        for (int kc = 0; kc < 4; ++kc)
            ax[kc].u4 = *(const uint4*)&smem[XOFF + (wid * 32 + cl) * 72 + kc * 16 + h5 * 8];
        // K proj: D col = ck = cl, rows = tok
        f32x16 kd = mfma32(ax[0], wkB[0], z16);
        kd = mfma32(ax[1], wkB[1], kd);
        kd = mfma32(ax[2], wkB[2], kd);
        kd = mfma32(ax[3], wkB[3], kd);
#pragma unroll
        for (int r = 0; r < 16; ++r) {
            const int row = tokb + (r & 3) + 8 * (r >> 2) + 4 * h5;
            smem[kidx(row, cl >> 3) + (cl & 7)] = (u16)cvtpk(kd[r] + kbias, kd[r] + kbias);
        }
        // V proj: D col = cv, rows = tok -> V^T[cv][tok] packed uint2
#pragma unroll
        for (int nb = 0; nb < 2; ++nb) {
            f32x16 vd = mfma32(ax[0], wvB[nb][0], z16);
            vd = mfma32(ax[1], wvB[nb][1], vd);
            vd = mfma32(ax[2], wvB[nb][2], vd);
            vd = mfma32(ax[3], wvB[nb][3], vd);
            const int cv = nb * 32 + cl;
            const float vb = vbias[nb];
#pragma unroll
            for (int rq = 0; rq < 4; ++rq) {
                uint2 pk;
                pk.x = cvtpk(vd[rq * 4 + 0] + vb, vd[rq * 4 + 1] + vb);
                pk.y = cvtpk(vd[rq * 4 + 2] + vb, vd[rq * 4 + 3] + vb);
                *(uint2*)&smem[VOFF + cv * 520 + tokb + rq * 8 + 4 * h5] = pk;
            }
        }
        if (cc == 0) {
            __syncthreads();                  // (2) X0 readers done
            STX()
            __syncthreads();                  // (3) X1 visible
        }
    }
    __syncthreads();                          // (4) K/V complete

    // ---- attention: wave owns q = wid*64 + qb*32 + cl; m in 16 chunks of 32 ----
    B8 qB[2][2];
#pragma unroll
    for (int qb = 0; qb < 2; ++qb)
#pragma unroll
        for (int kc = 0; kc < 2; ++kc)
            qB[qb][kc].u4 = *(const uint4*)&smem[kidx(wid * 64 + qb * 32 + cl, 2 * kc + h5)];

    f32x16 ctx00 = z16, ctx01 = z16, ctx10 = z16, ctx11 = z16;  // ctx[cb][qb]
    float lsum0 = 0.f, lsum1 = 0.f;

#pragma unroll 2
    for (int ci = 0; ci < 16; ++ci) {
        const int m0 = ci * 32;
        B8 kA0, kA1, va00, va01, va10, va11;
        kA0.u4 = *(const uint4*)&smem[kidx(m0 + cl, h5)];
        kA1.u4 = *(const uint4*)&smem[kidx(m0 + cl, 2 + h5)];
        va00.u4 = *(const uint4*)&smem[VOFF + cl * 520 + m0 + h5 * 8];
        va01.u4 = *(const uint4*)&smem[VOFF + cl * 520 + m0 + 16 + h5 * 8];
        va10.u4 = *(const uint4*)&smem[VOFF + (32 + cl) * 520 + m0 + h5 * 8];
        va11.u4 = *(const uint4*)&smem[VOFF + (32 + cl) * 520 + m0 + 16 + h5 * 8];

        // S^T[m][q] log2-domain: rows m in-lane, col q = cl
        f32x16 s0 = mfma32(kA0, qB[0][0], z16);
        s0 = mfma32(kA1, qB[0][1], s0);
        f32x16 s1 = mfma32(kA0, qB[1][0], z16);
        s1 = mfma32(kA1, qB[1][1], s1);

        float p[16];
        B8 pb00, pb01, pb10, pb11;
#pragma unroll
        for (int i = 0; i < 16; ++i) p[i] = ex2(s0[i]);
        lsum0 += (((p[0]+p[1])+(p[2]+p[3]))+((p[4]+p[5])+(p[6]+p[7])))
               + (((p[8]+p[9])+(p[10]+p[11]))+((p[12]+p[13])+(p[14]+p[15])));
        build_b(p, pb00, pb01);
#pragma unroll
        for (int i = 0; i < 16; ++i) p[i] = ex2(s1[i]);
        lsum1 += (((p[0]+p[1])+(p[2]+p[3]))+((p[4]+p[5])+(p[6]+p[7])))
               + (((p[8]+p[9])+(p[10]+p[11]))+((p[12]+p[13])+(p[14]+p[15])));
        build_b(p, pb10, pb11);

        ctx00 = mfma32(va00, pb00, ctx00); ctx00 = mfma32(va01, pb01, ctx00);
        ctx10 = mfma32(va10, pb00, ctx10); ctx10 = mfma32(va11, pb01, ctx10);
        ctx01 = mfma32(va00, pb10, ctx01); ctx01 = mfma32(va01, pb11, ctx01);
        ctx11 = mfma32(va10, pb10, ctx11); ctx11 = mfma32(va11, pb11, ctx11);
    }

    lsum0 += __shfl_xor(lsum0, 32);
    lsum1 += __shfl_xor(lsum1, 32);
    const float inv0 = 1.0f / lsum0;
    const float inv1 = 1.0f / lsum1;

    // out-proj A-frags (wo) + ctx -> B-frags in registers
    B8 aw[2][4];
#pragma unroll
    for (int cob = 0; cob < 2; ++cob)
#pragma unroll
        for (int kc = 0; kc < 4; ++kc)
            aw[cob][kc] = load_w8(wo + (cob * 32 + cl) * 64 + kc * 16 + h5 * 8, 1.0f);

    float pn[16];
    B8 cq0[4], cq1[4];   // B-frags per qb over k=cv chunks 0..3
#pragma unroll
    for (int i = 0; i < 16; ++i) pn[i] = ctx00[i] * inv0;
    build_b(pn, cq0[0], cq0[1]);
#pragma unroll
    for (int i = 0; i < 16; ++i) pn[i] = ctx10[i] * inv0;
    build_b(pn, cq0[2], cq0[3]);
#pragma unroll
    for (int i = 0; i < 16; ++i) pn[i] = ctx01[i] * inv1;
    build_b(pn, cq1[0], cq1[1]);
#pragma unroll
    for (int i = 0; i < 16; ++i) pn[i] = ctx11[i] * inv1;
    build_b(pn, cq1[2], cq1[3]);

    __syncthreads();                          // (5) K/V readers done; LDS -> fout slots

    float* fout = (float*)((char*)smem + wid * 16384);   // [64 co][64 q] f32
#pragma unroll
    for (int cob = 0; cob < 2; ++cob) {
        f32x16 od0 = mfma32(aw[cob][0], cq0[0], z16);
        od0 = mfma32(aw[cob][1], cq0[1], od0);
        od0 = mfma32(aw[cob][2], cq0[2], od0);
        od0 = mfma32(aw[cob][3], cq0[3], od0);
        f32x16 od1 = mfma32(aw[cob][0], cq1[0], z16);
        od1 = mfma32(aw[cob][1], cq1[1], od1);
        od1 = mfma32(aw[cob][2], cq1[2], od1);
        od1 = mfma32(aw[cob][3], cq1[3], od1);
#pragma unroll
        for (int rq = 0; rq < 4; ++rq) {
            const float4 b4 = *(const float4*)(bo + cob * 32 + rq * 8 + h5 * 4);
            const float bb[4] = { b4.x, b4.y, b4.z, b4.w };
#pragma unroll
            for (int i = 0; i < 4; ++i) {
                const int row = cob * 32 + rq * 8 + h5 * 4 + i;
                fout[row * 64 + cl]      = od0[rq * 4 + i] + bb[i];
                fout[row * 64 + 32 + cl] = od1[rq * 4 + i] + bb[i];
            }
        }
    }

    // coalesced global store: wave = hb row; q = wb*8+db
    float* outw = out + base_vox + (size_t)wid * 4096;
    const int lq = lane >> 4, lr = lane & 15;
#pragma unroll
    for (int it = 0; it < 16; ++it) {
        const int co = it * 4 + lq;
        const float4 v4 = *(const float4*)&fout[co * 64 + lr * 4];
        const int wb = lr >> 1, db0 = (lr & 1) * 4;
        *(float4*)&outw[(size_t)co * 262144 + wb * 64 + db0] = v4;
    }
}

extern "C" void kernel_launch(void* const* d_in, const int* in_sizes, int n_in,
                              void* d_out, int out_size, void* d_ws, size_t ws_size,
                              hipStream_t stream) {
    const float* x  = (const float*)d_in[0];
    const float* wk = (const float*)d_in[1];
    const float* bk = (const float*)d_in[2];
    const float* wv = (const float*)d_in[3];
    const float* bv = (const float*)d_in[4];
    const float* wo = (const float*)d_in[5];
    const float* bo = (const float*)d_in[6];
    float* o = (float*)d_out;
    psab_fused<<<dim3(512), dim3(512), 0, stream>>>(x, wk, bk, wv, bv, wo, bo, o);
}